// Round 1
// baseline (433.956 us; speedup 1.0000x reference)
//
#include <hip/hip_runtime.h>
#include <math.h>

// Problem constants
#define SS   256   // sequence length S
#define EMBD 512
#define HIDD 256
#define NHD  8
#define DHD  32
#define BB   8

// ---------------------------------------------------------------------------
// K1: h = me @ enc_w1^T + b1 ; LayerNorm ; relu -> Rout   (8 rows per block)
// ---------------------------------------------------------------------------
__global__ __launch_bounds__(256) void k_enc1_ln(
    const float* __restrict__ me, const float* __restrict__ w1,
    const float* __restrict__ b1, const float* __restrict__ g,
    const float* __restrict__ lb, float* __restrict__ Rout) {
  __shared__ float x[8 * 512];
  __shared__ float redA[4], redB[4];
  int j = threadIdx.x;
  int row0 = blockIdx.x * 8;
  const float4* src = (const float4*)(me + (size_t)row0 * 512);
  float4* dst = (float4*)x;
#pragma unroll
  for (int i = 0; i < 4; ++i) dst[j + i * 256] = src[j + i * 256];
  __syncthreads();
  const float4* w4 = (const float4*)(w1 + (size_t)j * 512);
  float acc[8];
  float bj = b1[j];
#pragma unroll
  for (int r = 0; r < 8; ++r) acc[r] = bj;
  for (int k4 = 0; k4 < 128; ++k4) {
    float4 w = w4[k4];
    int k = k4 * 4;
#pragma unroll
    for (int r = 0; r < 8; ++r) {
      const float* xr = x + r * 512;
      acc[r] += xr[k] * w.x + xr[k + 1] * w.y + xr[k + 2] * w.z + xr[k + 3] * w.w;
    }
  }
  int lane = j & 63, wv = j >> 6;
  float gj = g[j], lbj = lb[j];
  for (int r = 0; r < 8; ++r) {
    float v = acc[r];
    float s1 = v, s2 = v * v;
#pragma unroll
    for (int o = 32; o > 0; o >>= 1) {
      s1 += __shfl_down(s1, o, 64);
      s2 += __shfl_down(s2, o, 64);
    }
    if (lane == 0) { redA[wv] = s1; redB[wv] = s2; }
    __syncthreads();
    float S1 = redA[0] + redA[1] + redA[2] + redA[3];
    float S2 = redB[0] + redB[1] + redB[2] + redB[3];
    __syncthreads();
    float mu = S1 * (1.f / 256.f);
    float var = S2 * (1.f / 256.f) - mu * mu;
    float y = (v - mu) * rsqrtf(var + 1e-5f) * gj + lbj;
    Rout[(size_t)(row0 + r) * 256 + j] = fmaxf(y, 0.f);
  }
}

// ---------------------------------------------------------------------------
// Generic 256->256 row GEMM: Y = X @ W^T + bias    (8 rows per block)
// ---------------------------------------------------------------------------
__global__ __launch_bounds__(256) void k_gemm256(
    const float* __restrict__ X, const float* __restrict__ W,
    const float* __restrict__ Bias, float* __restrict__ Y) {
  __shared__ float x[8 * 256];
  int j = threadIdx.x;
  int row0 = blockIdx.x * 8;
  const float4* src = (const float4*)(X + (size_t)row0 * 256);
  float4* dst = (float4*)x;
  dst[j] = src[j];
  dst[j + 256] = src[j + 256];
  __syncthreads();
  const float4* w4 = (const float4*)(W + (size_t)j * 256);
  float acc[8];
  float bj = Bias[j];
#pragma unroll
  for (int r = 0; r < 8; ++r) acc[r] = bj;
  for (int k4 = 0; k4 < 64; ++k4) {
    float4 w = w4[k4];
    int k = k4 * 4;
#pragma unroll
    for (int r = 0; r < 8; ++r) {
      const float* xr = x + r * 256;
      acc[r] += xr[k] * w.x + xr[k + 1] * w.y + xr[k + 2] * w.z + xr[k + 3] * w.w;
    }
  }
#pragma unroll
  for (int r = 0; r < 8; ++r) Y[(size_t)(row0 + r) * 256 + j] = acc[r];
}

// ---------------------------------------------------------------------------
// K3: qkv = mf @ in_proj_w^T + b   (256 -> 768, 8 rows per block)
// ---------------------------------------------------------------------------
__global__ __launch_bounds__(256) void k_qkv(
    const float* __restrict__ X, const float* __restrict__ W,
    const float* __restrict__ Bias, float* __restrict__ Y) {
  __shared__ float x[8 * 256];
  int j = threadIdx.x;
  int row0 = blockIdx.x * 8;
  const float4* src = (const float4*)(X + (size_t)row0 * 256);
  float4* dst = (float4*)x;
  dst[j] = src[j];
  dst[j + 256] = src[j + 256];
  __syncthreads();
  for (int part = 0; part < 3; ++part) {
    int o = part * 256 + j;
    const float4* w4 = (const float4*)(W + (size_t)o * 256);
    float acc[8];
    float bj = Bias[o];
#pragma unroll
    for (int r = 0; r < 8; ++r) acc[r] = bj;
    for (int k4 = 0; k4 < 64; ++k4) {
      float4 w = w4[k4];
      int k = k4 * 4;
#pragma unroll
      for (int r = 0; r < 8; ++r) {
        const float* xr = x + r * 256;
        acc[r] += xr[k] * w.x + xr[k + 1] * w.y + xr[k + 2] * w.z + xr[k + 3] * w.w;
      }
    }
#pragma unroll
    for (int r = 0; r < 8; ++r) Y[(size_t)(row0 + r) * 768 + o] = acc[r];
  }
}

// ---------------------------------------------------------------------------
// K4a: one block per (b,h,s): scores -> softmax -> attn row
// ---------------------------------------------------------------------------
__global__ __launch_bounds__(256) void k_attn_softmax(
    const float* __restrict__ qkv, float* __restrict__ attn) {
  __shared__ float q[32];
  __shared__ float red[4];
  int idx = blockIdx.x;  // (b*NH + h)*S + s
  int s = idx & 255, bh = idx >> 8, h = bh & 7, b = bh >> 3;
  int t = threadIdx.x;
  if (t < 32) q[t] = qkv[((size_t)(b * 256 + s)) * 768 + h * 32 + t];
  __syncthreads();
  const float4* k4 = (const float4*)(qkv + ((size_t)(b * 256 + t)) * 768 + 256 + h * 32);
  float sc = 0.f;
#pragma unroll
  for (int d4 = 0; d4 < 8; ++d4) {
    float4 kv = k4[d4];
    int d = d4 * 4;
    sc += q[d] * kv.x + q[d + 1] * kv.y + q[d + 2] * kv.z + q[d + 3] * kv.w;
  }
  sc *= 0.17677669529663689f;  // 1/sqrt(32)
  int lane = t & 63, wv = t >> 6;
  float m = sc;
#pragma unroll
  for (int o = 32; o > 0; o >>= 1) m = fmaxf(m, __shfl_down(m, o, 64));
  if (lane == 0) red[wv] = m;
  __syncthreads();
  m = fmaxf(fmaxf(red[0], red[1]), fmaxf(red[2], red[3]));
  float p = expf(sc - m);
  __syncthreads();
  float ssum = p;
#pragma unroll
  for (int o = 32; o > 0; o >>= 1) ssum += __shfl_down(ssum, o, 64);
  if (lane == 0) red[wv] = ssum;
  __syncthreads();
  ssum = red[0] + red[1] + red[2] + red[3];
  attn[(size_t)idx * 256 + t] = p / ssum;
}

// ---------------------------------------------------------------------------
// K4b: one block per (b,h): ctx = attn @ v, stored as (B,S,HID) layout
// ---------------------------------------------------------------------------
__global__ __launch_bounds__(256) void k_ctx(
    const float* __restrict__ attn, const float* __restrict__ qkv,
    float* __restrict__ ctx) {
  __shared__ float v[256 * 32];
  int bh = blockIdx.x;
  int h = bh & 7, b = bh >> 3;
  int tid = threadIdx.x;
  for (int i = tid; i < 8192; i += 256) {
    int t = i >> 5, d = i & 31;
    v[i] = qkv[((size_t)(b * 256 + t)) * 768 + 512 + h * 32 + d];
  }
  __syncthreads();
  int s = tid;
  const float* arow = attn + ((size_t)bh * 256 + s) * 256;
  float acc[32];
#pragma unroll
  for (int d = 0; d < 32; ++d) acc[d] = 0.f;
  for (int t = 0; t < 256; ++t) {
    float p = arow[t];
    const float4* vr = (const float4*)(v + t * 32);
#pragma unroll
    for (int d4 = 0; d4 < 8; ++d4) {
      float4 vv = vr[d4];
      acc[d4 * 4 + 0] += p * vv.x;
      acc[d4 * 4 + 1] += p * vv.y;
      acc[d4 * 4 + 2] += p * vv.z;
      acc[d4 * 4 + 3] += p * vv.w;
    }
  }
  float* crow = ctx + ((size_t)(b * 256 + s)) * 256 + h * 32;
#pragma unroll
  for (int d = 0; d < 32; ++d) crow[d] = acc[d];
}

// ---------------------------------------------------------------------------
// K4c: attn_weights = mean over heads -> directly into d_out segment
// ---------------------------------------------------------------------------
__global__ __launch_bounds__(256) void k_attn_mean(
    const float* __restrict__ attn, float* __restrict__ out_aw) {
  int idx = blockIdx.x * 256 + threadIdx.x;  // over B*S*S
  int b = idx >> 16;
  int st = idx & 65535;
  float s = 0.f;
#pragma unroll
  for (int h = 0; h < 8; ++h) s += attn[(((size_t)b * 8 + h) << 16) + st];
  out_aw[idx] = s * 0.125f;
}

// ---------------------------------------------------------------------------
// K6: pooled = mean over s of attended
// ---------------------------------------------------------------------------
__global__ __launch_bounds__(256) void k_pool(
    const float* __restrict__ att, float* __restrict__ pooled) {
  int b = blockIdx.x, j = threadIdx.x;
  float s = 0.f;
  for (int t = 0; t < 256; ++t) s += att[((size_t)(b * 256 + t)) * 256 + j];
  pooled[b * 256 + j] = s * (1.f / 256.f);
}

// ---------------------------------------------------------------------------
// K7: cons & hall heads (one block per b, 128 threads)
// ---------------------------------------------------------------------------
__global__ __launch_bounds__(128) void k_heads(
    const float* __restrict__ pooled,
    const float* __restrict__ cw1, const float* __restrict__ cb1,
    const float* __restrict__ cw2, const float* __restrict__ cb2,
    const float* __restrict__ hw1, const float* __restrict__ hb1,
    const float* __restrict__ hw2, const float* __restrict__ hb2,
    float* __restrict__ out) {
  int b = blockIdx.x, j = threadIdx.x;  // j in [0,128)
  __shared__ float p[256];
  __shared__ float red[4];
  p[j] = pooled[b * 256 + j];
  p[j + 128] = pooled[b * 256 + j + 128];
  __syncthreads();
  float ac = cb1[j], ah = hb1[j];
  for (int k = 0; k < 256; ++k) {
    float pv = p[k];
    ac += pv * cw1[j * 256 + k];
    ah += pv * hw1[j * 256 + k];
  }
  float vc = fmaxf(ac, 0.f) * cw2[j];
  float vh = fmaxf(ah, 0.f) * hw2[j];
#pragma unroll
  for (int o = 32; o > 0; o >>= 1) {
    vc += __shfl_down(vc, o, 64);
    vh += __shfl_down(vh, o, 64);
  }
  int lane = j & 63, wv = j >> 6;
  if (lane == 0) { red[wv] = vc; red[2 + wv] = vh; }
  __syncthreads();
  if (j == 0) {
    float c = red[0] + red[1] + cb2[0];
    float hh = red[2] + red[3] + hb2[0];
    out[b] = 1.f / (1.f + expf(-c));
    out[8 + b] = 1.f / (1.f + expf(-hh));
  }
}

// ---------------------------------------------------------------------------
// K8: a = mf @ Wa^T ; b = mf @ Wb^T (con_w1 split) — 8 rows per block
// ---------------------------------------------------------------------------
__global__ __launch_bounds__(256) void k_ab(
    const float* __restrict__ X, const float* __restrict__ W,
    float* __restrict__ A, float* __restrict__ Bm) {
  __shared__ float x[8 * 256];
  int j = threadIdx.x;
  int row0 = blockIdx.x * 8;
  const float4* src = (const float4*)(X + (size_t)row0 * 256);
  float4* dst = (float4*)x;
  dst[j] = src[j];
  dst[j + 256] = src[j + 256];
  __syncthreads();
  const float4* wa4 = (const float4*)(W + (size_t)j * 512);
  const float4* wb4 = (const float4*)(W + (size_t)j * 512 + 256);
  float aa[8], ab[8];
#pragma unroll
  for (int r = 0; r < 8; ++r) { aa[r] = 0.f; ab[r] = 0.f; }
  for (int k4 = 0; k4 < 64; ++k4) {
    float4 wa = wa4[k4], wb = wb4[k4];
    int k = k4 * 4;
#pragma unroll
    for (int r = 0; r < 8; ++r) {
      const float* xr = x + r * 256;
      aa[r] += xr[k] * wa.x + xr[k + 1] * wa.y + xr[k + 2] * wa.z + xr[k + 3] * wa.w;
      ab[r] += xr[k] * wb.x + xr[k + 1] * wb.y + xr[k + 2] * wb.z + xr[k + 3] * wb.w;
    }
  }
#pragma unroll
  for (int r = 0; r < 8; ++r) {
    A[(size_t)(row0 + r) * 256 + j] = aa[r];
    Bm[(size_t)(row0 + r) * 256 + j] = ab[r];
  }
}

// ---------------------------------------------------------------------------
// K9: pair scores -> symmetric M (one block per (b,i), thread j handles pair)
// ---------------------------------------------------------------------------
__global__ __launch_bounds__(256) void k_pairs(
    const float* __restrict__ amat, const float* __restrict__ bmat,
    const float* __restrict__ cb1, const float* __restrict__ cw2,
    const float* __restrict__ cb2, float* __restrict__ M) {
  int bi = blockIdx.x;
  int i = bi & 255, b = bi >> 8;
  int j = threadIdx.x;
  __shared__ float arow[256];
  __shared__ float w2[256];
  arow[j] = amat[((size_t)(b * 256 + i)) * 256 + j] + cb1[j];
  w2[j] = cw2[j];
  __syncthreads();
  float* Mb = M + ((size_t)b << 16);
  if (j == i) Mb[i * 256 + i] = 0.f;
  if (j > i) {
    const float4* b4 = (const float4*)(bmat + ((size_t)(b * 256 + j)) * 256);
    float s = 0.f;
    for (int d4 = 0; d4 < 64; ++d4) {
      float4 bv = b4[d4];
      int d = d4 * 4;
      s += fmaxf(arow[d] + bv.x, 0.f) * w2[d]
         + fmaxf(arow[d + 1] + bv.y, 0.f) * w2[d + 1]
         + fmaxf(arow[d + 2] + bv.z, 0.f) * w2[d + 2]
         + fmaxf(arow[d + 3] + bv.w, 0.f) * w2[d + 3];
    }
    float sc = 1.f / (1.f + expf(-(s + cb2[0])));
    Mb[i * 256 + j] = sc;
    Mb[j * 256 + i] = sc;
  }
}

// ---------------------------------------------------------------------------
extern "C" void kernel_launch(void* const* d_in, const int* in_sizes, int n_in,
                              void* d_out, int out_size, void* d_ws, size_t ws_size,
                              hipStream_t stream) {
  const float* me        = (const float*)d_in[0];
  const float* enc_w1    = (const float*)d_in[1];
  const float* enc_b1    = (const float*)d_in[2];
  const float* ln_g      = (const float*)d_in[3];
  const float* ln_b      = (const float*)d_in[4];
  const float* enc_w2    = (const float*)d_in[5];
  const float* enc_b2    = (const float*)d_in[6];
  const float* in_proj_w = (const float*)d_in[7];
  const float* in_proj_b = (const float*)d_in[8];
  const float* out_w     = (const float*)d_in[9];
  const float* out_b     = (const float*)d_in[10];
  const float* cons_w1   = (const float*)d_in[11];
  const float* cons_b1   = (const float*)d_in[12];
  const float* cons_w2   = (const float*)d_in[13];
  const float* cons_b2   = (const float*)d_in[14];
  const float* hall_w1   = (const float*)d_in[15];
  const float* hall_b1   = (const float*)d_in[16];
  const float* hall_w2   = (const float*)d_in[17];
  const float* hall_b2   = (const float*)d_in[18];
  const float* con_w1    = (const float*)d_in[19];
  const float* con_b1    = (const float*)d_in[20];
  const float* con_w2    = (const float*)d_in[21];
  const float* con_b2    = (const float*)d_in[22];

  // workspace layout (floats); total ~8.92M floats = ~34 MiB
  float* ws = (float*)d_ws;
  float* r      = ws;                 // 524288
  float* mf     = ws + 524288;        // 524288
  float* qkv    = ws + 1048576;       // 1572864
  float* attn   = ws + 2621440;       // 4194304
  float* ctx    = ws + 6815744;       // 524288
  float* att    = ws + 7340032;       // 524288
  float* pooled = ws + 7864320;       // 2048
  float* amat   = ws + 7866368;       // 524288
  float* bmat   = ws + 8390656;       // 524288

  float* out    = (float*)d_out;
  float* out_M  = out + 16;            // 8 cons + 8 hall before it
  float* out_aw = out + 16 + 524288;

  k_enc1_ln<<<256, 256, 0, stream>>>(me, enc_w1, enc_b1, ln_g, ln_b, r);
  k_gemm256<<<256, 256, 0, stream>>>(r, enc_w2, enc_b2, mf);
  k_qkv<<<256, 256, 0, stream>>>(mf, in_proj_w, in_proj_b, qkv);
  k_attn_softmax<<<16384, 256, 0, stream>>>(qkv, attn);
  k_ctx<<<64, 256, 0, stream>>>(attn, qkv, ctx);
  k_attn_mean<<<2048, 256, 0, stream>>>(attn, out_aw);
  k_gemm256<<<256, 256, 0, stream>>>(ctx, out_w, out_b, att);
  k_pool<<<8, 256, 0, stream>>>(att, pooled);
  k_heads<<<8, 128, 0, stream>>>(pooled, cons_w1, cons_b1, cons_w2, cons_b2,
                                 hall_w1, hall_b1, hall_w2, hall_b2, out);
  k_ab<<<256, 256, 0, stream>>>(mf, con_w1, amat, bmat);
  k_pairs<<<2048, 256, 0, stream>>>(amat, bmat, con_b1, con_w2, con_b2, out_M);
}

// Round 2
// 328.684 us; speedup vs baseline: 1.3203x; 1.3203x over previous
//
#include <hip/hip_runtime.h>
#include <math.h>

// ---------------------------------------------------------------------------
// K1: h = me @ enc_w1^T + b1 ; LayerNorm ; relu -> Rout   (8 rows per block)
// ---------------------------------------------------------------------------
__global__ __launch_bounds__(256) void k_enc1_ln(
    const float* __restrict__ me, const float* __restrict__ w1,
    const float* __restrict__ b1, const float* __restrict__ g,
    const float* __restrict__ lb, float* __restrict__ Rout) {
  __shared__ float x[8 * 512];
  __shared__ float redA[4], redB[4];
  int j = threadIdx.x;
  int row0 = blockIdx.x * 8;
  const float4* src = (const float4*)(me + (size_t)row0 * 512);
  float4* dst = (float4*)x;
#pragma unroll
  for (int i = 0; i < 4; ++i) dst[j + i * 256] = src[j + i * 256];
  __syncthreads();
  const float4* w4 = (const float4*)(w1 + (size_t)j * 512);
  float acc[8];
  float bj = b1[j];
#pragma unroll
  for (int r = 0; r < 8; ++r) acc[r] = bj;
  for (int k4 = 0; k4 < 128; ++k4) {
    float4 w = w4[k4];
    int k = k4 * 4;
#pragma unroll
    for (int r = 0; r < 8; ++r) {
      const float* xr = x + r * 512;
      acc[r] += xr[k] * w.x + xr[k + 1] * w.y + xr[k + 2] * w.z + xr[k + 3] * w.w;
    }
  }
  int lane = j & 63, wv = j >> 6;
  float gj = g[j], lbj = lb[j];
  for (int r = 0; r < 8; ++r) {
    float v = acc[r];
    float s1 = v, s2 = v * v;
#pragma unroll
    for (int o = 32; o > 0; o >>= 1) {
      s1 += __shfl_down(s1, o, 64);
      s2 += __shfl_down(s2, o, 64);
    }
    if (lane == 0) { redA[wv] = s1; redB[wv] = s2; }
    __syncthreads();
    float S1 = redA[0] + redA[1] + redA[2] + redA[3];
    float S2 = redB[0] + redB[1] + redB[2] + redB[3];
    __syncthreads();
    float mu = S1 * (1.f / 256.f);
    float var = S2 * (1.f / 256.f) - mu * mu;
    float y = (v - mu) * rsqrtf(var + 1e-5f) * gj + lbj;
    Rout[(size_t)(row0 + r) * 256 + j] = fmaxf(y, 0.f);
  }
}

// ---------------------------------------------------------------------------
// Generic 256->256 row GEMM: Y = X @ W^T + bias    (8 rows per block)
// ---------------------------------------------------------------------------
__global__ __launch_bounds__(256) void k_gemm256(
    const float* __restrict__ X, const float* __restrict__ W,
    const float* __restrict__ Bias, float* __restrict__ Y) {
  __shared__ float x[8 * 256];
  int j = threadIdx.x;
  int row0 = blockIdx.x * 8;
  const float4* src = (const float4*)(X + (size_t)row0 * 256);
  float4* dst = (float4*)x;
  dst[j] = src[j];
  dst[j + 256] = src[j + 256];
  __syncthreads();
  const float4* w4 = (const float4*)(W + (size_t)j * 256);
  float acc[8];
  float bj = Bias[j];
#pragma unroll
  for (int r = 0; r < 8; ++r) acc[r] = bj;
  for (int k4 = 0; k4 < 64; ++k4) {
    float4 w = w4[k4];
    int k = k4 * 4;
#pragma unroll
    for (int r = 0; r < 8; ++r) {
      const float* xr = x + r * 256;
      acc[r] += xr[k] * w.x + xr[k + 1] * w.y + xr[k + 2] * w.z + xr[k + 3] * w.w;
    }
  }
#pragma unroll
  for (int r = 0; r < 8; ++r) Y[(size_t)(row0 + r) * 256 + j] = acc[r];
}

// ---------------------------------------------------------------------------
// K3: qkv = mf @ in_proj_w^T + b   (256 -> 768, 8 rows per block)
// ---------------------------------------------------------------------------
__global__ __launch_bounds__(256) void k_qkv(
    const float* __restrict__ X, const float* __restrict__ W,
    const float* __restrict__ Bias, float* __restrict__ Y) {
  __shared__ float x[8 * 256];
  int j = threadIdx.x;
  int row0 = blockIdx.x * 8;
  const float4* src = (const float4*)(X + (size_t)row0 * 256);
  float4* dst = (float4*)x;
  dst[j] = src[j];
  dst[j + 256] = src[j + 256];
  __syncthreads();
  for (int part = 0; part < 3; ++part) {
    int o = part * 256 + j;
    const float4* w4 = (const float4*)(W + (size_t)o * 256);
    float acc[8];
    float bj = Bias[o];
#pragma unroll
    for (int r = 0; r < 8; ++r) acc[r] = bj;
    for (int k4 = 0; k4 < 64; ++k4) {
      float4 w = w4[k4];
      int k = k4 * 4;
#pragma unroll
      for (int r = 0; r < 8; ++r) {
        const float* xr = x + r * 256;
        acc[r] += xr[k] * w.x + xr[k + 1] * w.y + xr[k + 2] * w.z + xr[k + 3] * w.w;
      }
    }
#pragma unroll
    for (int r = 0; r < 8; ++r) Y[(size_t)(row0 + r) * 768 + o] = acc[r];
  }
}

// ---------------------------------------------------------------------------
// K4a v2: scores + softmax, wave-per-8-rows, no barriers in hot path.
// grid = (b,h,sg) = 8*8*8 = 512 blocks, 256 threads (4 waves x 8 rows = 32 rows)
// ---------------------------------------------------------------------------
__global__ __launch_bounds__(256) void k_attn2(
    const float* __restrict__ qkv, float* __restrict__ attn) {
  __shared__ float qs[32 * 32];
  int blk = blockIdx.x;
  int sg = blk & 7, bh = blk >> 3, h = bh & 7, b = bh >> 3;
  int tid = threadIdx.x;
  {
    int r = tid >> 3, c4 = tid & 7;
    float4 v = *(const float4*)(qkv + ((size_t)(b * 256 + sg * 32 + r)) * 768 + h * 32 + c4 * 4);
    *(float4*)&qs[r * 32 + c4 * 4] = v;
  }
  __syncthreads();
  int lane = tid & 63, w = tid >> 6;
  int r0 = w * 8;
  float sc[8][4];
#pragma unroll
  for (int r = 0; r < 8; ++r)
#pragma unroll
    for (int tt = 0; tt < 4; ++tt) sc[r][tt] = 0.f;
#pragma unroll
  for (int tt = 0; tt < 4; ++tt) {
    int t = tt * 64 + lane;
    const float4* kp = (const float4*)(qkv + ((size_t)(b * 256 + t)) * 768 + 256 + h * 32);
#pragma unroll
    for (int d4 = 0; d4 < 8; ++d4) {
      float4 kv = kp[d4];
#pragma unroll
      for (int r = 0; r < 8; ++r) {
        float4 qv = *(const float4*)&qs[(r0 + r) * 32 + d4 * 4];
        sc[r][tt] += qv.x * kv.x + qv.y * kv.y + qv.z * kv.z + qv.w * kv.w;
      }
    }
  }
  const float scale = 0.17677669529663689f;
  float* arow_base = attn + ((size_t)(bh * 256 + sg * 32 + r0)) * 256;
  for (int r = 0; r < 8; ++r) {
    float v0 = sc[r][0] * scale, v1 = sc[r][1] * scale;
    float v2 = sc[r][2] * scale, v3 = sc[r][3] * scale;
    float m = fmaxf(fmaxf(v0, v1), fmaxf(v2, v3));
#pragma unroll
    for (int o = 32; o > 0; o >>= 1) m = fmaxf(m, __shfl_xor(m, o, 64));
    float e0 = expf(v0 - m), e1 = expf(v1 - m), e2 = expf(v2 - m), e3 = expf(v3 - m);
    float s = e0 + e1 + e2 + e3;
#pragma unroll
    for (int o = 32; o > 0; o >>= 1) s += __shfl_xor(s, o, 64);
    float inv = 1.f / s;
    float* arow = arow_base + r * 256;
    arow[lane] = e0 * inv;
    arow[64 + lane] = e1 * inv;
    arow[128 + lane] = e2 * inv;
    arow[192 + lane] = e3 * inv;
  }
}

// ---------------------------------------------------------------------------
// K4b v2: ctx = attn @ v. grid = (b,h,s-half,d-half) = 256 blocks.
// wave = d-group (4 d's of the 16-d half), lane = s-pair (2 rows).
// ---------------------------------------------------------------------------
__global__ __launch_bounds__(256) void k_ctx2(
    const float* __restrict__ attn, const float* __restrict__ qkv,
    float* __restrict__ ctx) {
  __shared__ float vs[256 * 16];
  __shared__ float ps[128 * 33];
  int blk = blockIdx.x;
  int dh = blk & 1, sh = (blk >> 1) & 1, bh = blk >> 2, h = bh & 7, b = bh >> 3;
  int tid = threadIdx.x;
#pragma unroll
  for (int k = 0; k < 4; ++k) {
    int f = tid + k * 256;
    int t = f >> 2, c4 = f & 3;
    float4 v = *(const float4*)(qkv + ((size_t)(b * 256 + t)) * 768 + 512 + h * 32 + dh * 16 + c4 * 4);
    *(float4*)&vs[t * 16 + c4 * 4] = v;
  }
  int lane = tid & 63, wv = tid >> 6;
  float a0x = 0, a0y = 0, a0z = 0, a0w = 0;
  float a1x = 0, a1y = 0, a1z = 0, a1w = 0;
  int s0l = 2 * lane, s1l = 2 * lane + 1;
  const float* abase = attn + (((size_t)bh) << 16) + (size_t)(sh * 128) * 256;
  for (int tc = 0; tc < 8; ++tc) {
    __syncthreads();
#pragma unroll
    for (int k = 0; k < 4; ++k) {
      int f = tid + k * 256;
      int r = f >> 3, c4 = f & 7;
      float4 p = *(const float4*)(abase + (size_t)r * 256 + tc * 32 + c4 * 4);
      int la = r * 33 + c4 * 4;
      ps[la] = p.x; ps[la + 1] = p.y; ps[la + 2] = p.z; ps[la + 3] = p.w;
    }
    __syncthreads();
#pragma unroll
    for (int t = 0; t < 32; ++t) {
      int tg = tc * 32 + t;
      float4 vv = *(const float4*)&vs[tg * 16 + wv * 4];
      float p0 = ps[s0l * 33 + t], p1 = ps[s1l * 33 + t];
      a0x += p0 * vv.x; a0y += p0 * vv.y; a0z += p0 * vv.z; a0w += p0 * vv.w;
      a1x += p1 * vv.x; a1y += p1 * vv.y; a1z += p1 * vv.z; a1w += p1 * vv.w;
    }
  }
  int srow0 = sh * 128 + s0l;
  float* c0 = ctx + ((size_t)(b * 256 + srow0)) * 256 + h * 32 + dh * 16 + wv * 4;
  float* c1 = c0 + 256;
  c0[0] = a0x; c0[1] = a0y; c0[2] = a0z; c0[3] = a0w;
  c1[0] = a1x; c1[1] = a1y; c1[2] = a1z; c1[3] = a1w;
}

// ---------------------------------------------------------------------------
// K4c: attn_weights = mean over heads (float4)
// ---------------------------------------------------------------------------
__global__ __launch_bounds__(256) void k_attn_mean(
    const float* __restrict__ attn, float* __restrict__ out_aw) {
  int idx = blockIdx.x * 256 + threadIdx.x;  // over B*S*S/4 = 131072
  int b = idx >> 14;
  int st4 = idx & 16383;
  const float4* base = (const float4*)(attn + ((size_t)b << 19));
  float sx = 0, sy = 0, sz = 0, sw = 0;
#pragma unroll
  for (int h = 0; h < 8; ++h) {
    float4 v = base[h * 16384 + st4];
    sx += v.x; sy += v.y; sz += v.z; sw += v.w;
  }
  float4 r; r.x = sx * 0.125f; r.y = sy * 0.125f; r.z = sz * 0.125f; r.w = sw * 0.125f;
  ((float4*)out_aw)[idx] = r;
}

// ---------------------------------------------------------------------------
// K6: pooled = mean over s of attended
// ---------------------------------------------------------------------------
__global__ __launch_bounds__(256) void k_pool(
    const float* __restrict__ att, float* __restrict__ pooled) {
  int b = blockIdx.x, j = threadIdx.x;
  float s = 0.f;
  for (int t = 0; t < 256; ++t) s += att[((size_t)(b * 256 + t)) * 256 + j];
  pooled[b * 256 + j] = s * (1.f / 256.f);
}

// ---------------------------------------------------------------------------
// K7: cons & hall heads (one block per b, 128 threads)
// ---------------------------------------------------------------------------
__global__ __launch_bounds__(128) void k_heads(
    const float* __restrict__ pooled,
    const float* __restrict__ cw1, const float* __restrict__ cb1,
    const float* __restrict__ cw2, const float* __restrict__ cb2,
    const float* __restrict__ hw1, const float* __restrict__ hb1,
    const float* __restrict__ hw2, const float* __restrict__ hb2,
    float* __restrict__ out) {
  int b = blockIdx.x, j = threadIdx.x;  // j in [0,128)
  __shared__ float p[256];
  __shared__ float red[4];
  p[j] = pooled[b * 256 + j];
  p[j + 128] = pooled[b * 256 + j + 128];
  __syncthreads();
  float ac = cb1[j], ah = hb1[j];
  for (int k = 0; k < 256; ++k) {
    float pv = p[k];
    ac += pv * cw1[j * 256 + k];
    ah += pv * hw1[j * 256 + k];
  }
  float vc = fmaxf(ac, 0.f) * cw2[j];
  float vh = fmaxf(ah, 0.f) * hw2[j];
#pragma unroll
  for (int o = 32; o > 0; o >>= 1) {
    vc += __shfl_down(vc, o, 64);
    vh += __shfl_down(vh, o, 64);
  }
  int lane = j & 63, wv = j >> 6;
  if (lane == 0) { red[wv] = vc; red[2 + wv] = vh; }
  __syncthreads();
  if (j == 0) {
    float c = red[0] + red[1] + cb2[0];
    float hh = red[2] + red[3] + hb2[0];
    out[b] = 1.f / (1.f + expf(-c));
    out[8 + b] = 1.f / (1.f + expf(-hh));
  }
}

// ---------------------------------------------------------------------------
// K8: a = mf @ Wa^T + cb1 ; b = mf @ Wb^T  (con_w1 split) — 8 rows per block
// ---------------------------------------------------------------------------
__global__ __launch_bounds__(256) void k_ab(
    const float* __restrict__ X, const float* __restrict__ W,
    const float* __restrict__ cb1, float* __restrict__ A,
    float* __restrict__ Bm) {
  __shared__ float x[8 * 256];
  int j = threadIdx.x;
  int row0 = blockIdx.x * 8;
  const float4* src = (const float4*)(X + (size_t)row0 * 256);
  float4* dst = (float4*)x;
  dst[j] = src[j];
  dst[j + 256] = src[j + 256];
  __syncthreads();
  const float4* wa4 = (const float4*)(W + (size_t)j * 512);
  const float4* wb4 = (const float4*)(W + (size_t)j * 512 + 256);
  float aa[8], ab[8];
#pragma unroll
  for (int r = 0; r < 8; ++r) { aa[r] = 0.f; ab[r] = 0.f; }
  for (int k4 = 0; k4 < 64; ++k4) {
    float4 wa = wa4[k4], wb = wb4[k4];
    int k = k4 * 4;
#pragma unroll
    for (int r = 0; r < 8; ++r) {
      const float* xr = x + r * 256;
      aa[r] += xr[k] * wa.x + xr[k + 1] * wa.y + xr[k + 2] * wa.z + xr[k + 3] * wa.w;
      ab[r] += xr[k] * wb.x + xr[k + 1] * wb.y + xr[k + 2] * wb.z + xr[k + 3] * wb.w;
    }
  }
  float cb = cb1[j];
#pragma unroll
  for (int r = 0; r < 8; ++r) {
    A[(size_t)(row0 + r) * 256 + j] = aa[r] + cb;  // fold con_b1 into a
    Bm[(size_t)(row0 + r) * 256 + j] = ab[r];
  }
}

// ---------------------------------------------------------------------------
// K9 v2: pair scores, LDS-tiled 32x32 upper-triangular tiles.
// grid = b * 36 tile-pairs = 288 blocks; thread owns 2x2 pairs.
// amat already includes con_b1.
// ---------------------------------------------------------------------------
__global__ __launch_bounds__(256) void k_pairs(
    const float* __restrict__ amat, const float* __restrict__ bmat,
    const float* __restrict__ cw2, const float* __restrict__ cb2,
    float* __restrict__ M) {
  __shared__ float As[32 * 130];
  __shared__ float Bs[32 * 130];
  __shared__ float w2s[256];
  int blk = blockIdx.x;
  int b = blk / 36, tix = blk % 36;
  int it = 0, rem = tix;
  while (rem >= 8 - it) { rem -= 8 - it; ++it; }
  int jt = it + rem;
  int tid = threadIdx.x;
  int tj = tid & 15, ti = tid >> 4;  // consecutive lanes vary j (coalescing)
  w2s[tid] = cw2[tid];
  float acc00 = 0, acc01 = 0, acc10 = 0, acc11 = 0;
  const float* Ab = amat + ((size_t)(b * 256 + it * 32)) * 256;
  const float* Bb = bmat + ((size_t)(b * 256 + jt * 32)) * 256;
  for (int ch = 0; ch < 2; ++ch) {
    __syncthreads();
#pragma unroll
    for (int k = 0; k < 4; ++k) {
      int f = tid + k * 256;       // 1024 float4 per tile-chunk
      int r = f >> 5, c4 = f & 31; // 32 f4 per row of 128 floats
      float4 va = *(const float4*)(Ab + (size_t)r * 256 + ch * 128 + c4 * 4);
      float4 vb = *(const float4*)(Bb + (size_t)r * 256 + ch * 128 + c4 * 4);
      int la = r * 130 + c4 * 4;
      *(float2*)&As[la] = make_float2(va.x, va.y);
      *(float2*)&As[la + 2] = make_float2(va.z, va.w);
      *(float2*)&Bs[la] = make_float2(vb.x, vb.y);
      *(float2*)&Bs[la + 2] = make_float2(vb.z, vb.w);
    }
    __syncthreads();
    const float* a0 = As + (2 * ti) * 130;
    const float* a1 = a0 + 130;
    const float* b0 = Bs + (2 * tj) * 130;
    const float* b1 = b0 + 130;
    const float* w2c = w2s + ch * 128;
    for (int d = 0; d < 128; d += 4) {
#pragma unroll
      for (int k = 0; k < 4; ++k) {
        float w = w2c[d + k];
        float av0 = a0[d + k], av1 = a1[d + k];
        float bv0 = b0[d + k], bv1 = b1[d + k];
        acc00 += fmaxf(av0 + bv0, 0.f) * w;
        acc01 += fmaxf(av0 + bv1, 0.f) * w;
        acc10 += fmaxf(av1 + bv0, 0.f) * w;
        acc11 += fmaxf(av1 + bv1, 0.f) * w;
      }
    }
  }
  float c2 = cb2[0];
  float s00 = 1.f / (1.f + expf(-(acc00 + c2)));
  float s01 = 1.f / (1.f + expf(-(acc01 + c2)));
  float s10 = 1.f / (1.f + expf(-(acc10 + c2)));
  float s11 = 1.f / (1.f + expf(-(acc11 + c2)));
  float* Mb = M + ((size_t)b << 16);
  int i0 = it * 32 + 2 * ti, i1 = i0 + 1;
  int j0 = jt * 32 + 2 * tj, j1 = j0 + 1;
  if (it != jt) {
    Mb[i0 * 256 + j0] = s00; Mb[j0 * 256 + i0] = s00;
    Mb[i0 * 256 + j1] = s01; Mb[j1 * 256 + i0] = s01;
    Mb[i1 * 256 + j0] = s10; Mb[j0 * 256 + i1] = s10;
    Mb[i1 * 256 + j1] = s11; Mb[j1 * 256 + i1] = s11;
  } else {
    if (j0 > i0) { Mb[i0 * 256 + j0] = s00; Mb[j0 * 256 + i0] = s00; }
    else if (j0 == i0) Mb[i0 * 256 + j0] = 0.f;
    if (j1 > i0) { Mb[i0 * 256 + j1] = s01; Mb[j1 * 256 + i0] = s01; }
    if (j0 > i1) { Mb[i1 * 256 + j0] = s10; Mb[j0 * 256 + i1] = s10; }
    if (j1 > i1) { Mb[i1 * 256 + j1] = s11; Mb[j1 * 256 + i1] = s11; }
    else if (j1 == i1) Mb[i1 * 256 + j1] = 0.f;
  }
}

// ---------------------------------------------------------------------------
extern "C" void kernel_launch(void* const* d_in, const int* in_sizes, int n_in,
                              void* d_out, int out_size, void* d_ws, size_t ws_size,
                              hipStream_t stream) {
  const float* me        = (const float*)d_in[0];
  const float* enc_w1    = (const float*)d_in[1];
  const float* enc_b1    = (const float*)d_in[2];
  const float* ln_g      = (const float*)d_in[3];
  const float* ln_b      = (const float*)d_in[4];
  const float* enc_w2    = (const float*)d_in[5];
  const float* enc_b2    = (const float*)d_in[6];
  const float* in_proj_w = (const float*)d_in[7];
  const float* in_proj_b = (const float*)d_in[8];
  const float* out_w     = (const float*)d_in[9];
  const float* out_b     = (const float*)d_in[10];
  const float* cons_w1   = (const float*)d_in[11];
  const float* cons_b1   = (const float*)d_in[12];
  const float* cons_w2   = (const float*)d_in[13];
  const float* cons_b2   = (const float*)d_in[14];
  const float* hall_w1   = (const float*)d_in[15];
  const float* hall_b1   = (const float*)d_in[16];
  const float* hall_w2   = (const float*)d_in[17];
  const float* hall_b2   = (const float*)d_in[18];
  const float* con_w1    = (const float*)d_in[19];
  const float* con_b1    = (const float*)d_in[20];
  const float* con_w2    = (const float*)d_in[21];
  const float* con_b2    = (const float*)d_in[22];

  // workspace layout (floats)
  float* ws = (float*)d_ws;
  float* r      = ws;                 // 524288
  float* mf     = ws + 524288;        // 524288
  float* qkv    = ws + 1048576;       // 1572864
  float* attn   = ws + 2621440;       // 4194304
  float* ctx    = ws + 6815744;       // 524288
  float* att    = ws + 7340032;       // 524288
  float* pooled = ws + 7864320;       // 2048
  float* amat   = ws + 7866368;       // 524288
  float* bmat   = ws + 8390656;       // 524288

  float* out    = (float*)d_out;
  float* out_M  = out + 16;
  float* out_aw = out + 16 + 524288;

  k_enc1_ln<<<256, 256, 0, stream>>>(me, enc_w1, enc_b1, ln_g, ln_b, r);
  k_gemm256<<<256, 256, 0, stream>>>(r, enc_w2, enc_b2, mf);
  k_qkv<<<256, 256, 0, stream>>>(mf, in_proj_w, in_proj_b, qkv);
  k_attn2<<<512, 256, 0, stream>>>(qkv, attn);
  k_ctx2<<<256, 256, 0, stream>>>(attn, qkv, ctx);
  k_attn_mean<<<512, 256, 0, stream>>>(attn, out_aw);
  k_gemm256<<<256, 256, 0, stream>>>(ctx, out_w, out_b, att);
  k_pool<<<8, 256, 0, stream>>>(att, pooled);
  k_heads<<<8, 128, 0, stream>>>(pooled, cons_w1, cons_b1, cons_w2, cons_b2,
                                 hall_w1, hall_b1, hall_w2, hall_b2, out);
  k_ab<<<256, 256, 0, stream>>>(mf, con_w1, con_b1, amat, bmat);
  k_pairs<<<288, 256, 0, stream>>>(amat, bmat, con_w2, con_b2, out_M);
}

// Round 3
// 237.048 us; speedup vs baseline: 1.8307x; 1.3866x over previous
//
#include <hip/hip_runtime.h>
#include <math.h>

typedef __attribute__((ext_vector_type(8))) short bf16x8;
typedef __attribute__((ext_vector_type(4))) float f32x4;

__device__ __forceinline__ short f2b(float f) {
  union { float f; unsigned u; } v; v.f = f;
  unsigned u = v.u + 0x7fffu + ((v.u >> 16) & 1u);
  return (short)(u >> 16);
}

// ---------------------------------------------------------------------------
// Shared MFMA K-loop: rows row0..row0+15 (fp32 X, stride=K, converted on the
// fly), wave w covers 64 cols (4 n-frags) of a 256-col strip of W (bf16,[N][K]).
// Frag layouts (guide-verified): A/B [idx=lane&15][k=(lane>>4)*8+j],
// D col=lane&15, row=(lane>>4)*4+reg.
// ---------------------------------------------------------------------------
template <int K>
__device__ __forceinline__ void mfma_rows16(
    const float* __restrict__ X, const unsigned short* __restrict__ Wb,
    int row0, int lane, int w, f32x4 acc[4]) {
  int m = lane & 15, q = lane >> 4;
  const float* ap = X + (size_t)(row0 + m) * K + q * 8;
#pragma unroll
  for (int ks = 0; ks < K; ks += 32, ap += 32) {
    float4 a01 = *(const float4*)ap;
    float4 a23 = *(const float4*)(ap + 4);
    bf16x8 af;
    af[0] = f2b(a01.x); af[1] = f2b(a01.y); af[2] = f2b(a01.z); af[3] = f2b(a01.w);
    af[4] = f2b(a23.x); af[5] = f2b(a23.y); af[6] = f2b(a23.z); af[7] = f2b(a23.w);
#pragma unroll
    for (int nt = 0; nt < 4; ++nt) {
      int n = w * 64 + nt * 16 + m;
      bf16x8 bf = *(const bf16x8*)(Wb + (size_t)n * K + ks + q * 8);
      acc[nt] = __builtin_amdgcn_mfma_f32_16x16x32_bf16(af, bf, acc[nt], 0, 0, 0);
    }
  }
}

// ---------------------------------------------------------------------------
// K0: convert weights to bf16 (con_w1 repacked to Wab[512][256])
// segments: enc_w1 131072 | enc_w2 65536 | in_proj_w 196608 | wab 131072
// ---------------------------------------------------------------------------
__global__ __launch_bounds__(256) void k_cvt(
    const float* __restrict__ w1, const float* __restrict__ w2,
    const float* __restrict__ wq, const float* __restrict__ wc,
    unsigned short* __restrict__ o) {
  int base = (blockIdx.x * 256 + threadIdx.x) * 4;
#pragma unroll
  for (int u = 0; u < 4; ++u) {
    int idx = base + u;
    float v;
    if (idx < 131072) v = w1[idx];
    else if (idx < 196608) v = w2[idx - 131072];
    else if (idx < 393216) v = wq[idx - 196608];
    else {
      int i = idx - 393216, n = i >> 8, k = i & 255;
      v = (n < 256) ? wc[n * 512 + k] : wc[(n - 256) * 512 + 256 + k];
    }
    o[idx] = (unsigned short)f2b(v);
  }
}

// ---------------------------------------------------------------------------
// K1: enc1 + LayerNorm + relu (MFMA, K=512, N=256 full width per block)
// ---------------------------------------------------------------------------
__global__ __launch_bounds__(256) void k_enc1_mfma(
    const float* __restrict__ me, const unsigned short* __restrict__ wb1,
    const float* __restrict__ b1, const float* __restrict__ g,
    const float* __restrict__ lb, float* __restrict__ Rout) {
  __shared__ float hh[16 * 260];
  int tid = threadIdx.x, lane = tid & 63, w = tid >> 6;
  int row0 = blockIdx.x * 16;
  f32x4 acc[4];
#pragma unroll
  for (int i = 0; i < 4; ++i) acc[i] = (f32x4){0.f, 0.f, 0.f, 0.f};
  mfma_rows16<512>(me, wb1, row0, lane, w, acc);
  int m = lane & 15, q = lane >> 4;
#pragma unroll
  for (int nt = 0; nt < 4; ++nt) {
    int col = w * 64 + nt * 16 + m;
    float bias = b1[col];
#pragma unroll
    for (int reg = 0; reg < 4; ++reg)
      hh[(q * 4 + reg) * 260 + col] = acc[nt][reg] + bias;
  }
  __syncthreads();
  float4 g4 = *(const float4*)(g + lane * 4);
  float4 lb4 = *(const float4*)(lb + lane * 4);
#pragma unroll
  for (int rr = 0; rr < 4; ++rr) {
    int r = w * 4 + rr;
    float4 v = *(const float4*)&hh[r * 260 + lane * 4];
    float s1 = v.x + v.y + v.z + v.w;
    float s2 = v.x * v.x + v.y * v.y + v.z * v.z + v.w * v.w;
#pragma unroll
    for (int o = 32; o > 0; o >>= 1) {
      s1 += __shfl_xor(s1, o, 64);
      s2 += __shfl_xor(s2, o, 64);
    }
    float mu = s1 * (1.f / 256.f);
    float var = s2 * (1.f / 256.f) - mu * mu;
    float rs = rsqrtf(var + 1e-5f);
    float4 y;
    y.x = fmaxf((v.x - mu) * rs * g4.x + lb4.x, 0.f);
    y.y = fmaxf((v.y - mu) * rs * g4.y + lb4.y, 0.f);
    y.z = fmaxf((v.z - mu) * rs * g4.z + lb4.z, 0.f);
    y.w = fmaxf((v.w - mu) * rs * g4.w + lb4.w, 0.f);
    *(float4*)(Rout + (size_t)(row0 + r) * 256 + lane * 4) = y;
  }
}

// ---------------------------------------------------------------------------
// K2: generic linear (K=256): Y[:, n0:n0+256] = X @ W^T + bias
// grid (rowblocks, nparts); used for enc2 (1 part) and qkv (3 parts)
// ---------------------------------------------------------------------------
__global__ __launch_bounds__(256) void k_lin256(
    const float* __restrict__ X, const unsigned short* __restrict__ Wb,
    const float* __restrict__ Bias, float* __restrict__ Y, int ldy) {
  int tid = threadIdx.x, lane = tid & 63, w = tid >> 6;
  int row0 = blockIdx.x * 16;
  int n0 = blockIdx.y * 256;
  f32x4 acc[4];
#pragma unroll
  for (int i = 0; i < 4; ++i) acc[i] = (f32x4){0.f, 0.f, 0.f, 0.f};
  mfma_rows16<256>(X, Wb + (size_t)n0 * 256, row0, lane, w, acc);
  int m = lane & 15, q = lane >> 4;
#pragma unroll
  for (int nt = 0; nt < 4; ++nt) {
    int col = n0 + w * 64 + nt * 16 + m;
    float bias = Bias[col];
#pragma unroll
    for (int reg = 0; reg < 4; ++reg) {
      int row = row0 + q * 4 + reg;
      Y[(size_t)row * ldy + col] = acc[nt][reg] + bias;
    }
  }
}

// ---------------------------------------------------------------------------
// K8: a/b pair projections via repacked Wab (N=512); part0 -> amat (+cb1),
// part1 -> bmat
// ---------------------------------------------------------------------------
__global__ __launch_bounds__(256) void k_ab_mfma(
    const float* __restrict__ X, const unsigned short* __restrict__ Wab,
    const float* __restrict__ cb1, float* __restrict__ A,
    float* __restrict__ Bm) {
  int tid = threadIdx.x, lane = tid & 63, w = tid >> 6;
  int row0 = blockIdx.x * 16;
  int part = blockIdx.y;
  f32x4 acc[4];
#pragma unroll
  for (int i = 0; i < 4; ++i) acc[i] = (f32x4){0.f, 0.f, 0.f, 0.f};
  mfma_rows16<256>(X, Wab + (size_t)part * 256 * 256, row0, lane, w, acc);
  int m = lane & 15, q = lane >> 4;
  float* Y = (part == 0) ? A : Bm;
#pragma unroll
  for (int nt = 0; nt < 4; ++nt) {
    int col = w * 64 + nt * 16 + m;
    float bias = (part == 0) ? cb1[col] : 0.f;
#pragma unroll
    for (int reg = 0; reg < 4; ++reg) {
      int row = row0 + q * 4 + reg;
      Y[(size_t)row * 256 + col] = acc[nt][reg] + bias;
    }
  }
}

// ---------------------------------------------------------------------------
// K4a: scores + softmax, wave-per-8-rows (fp32, unchanged)
// ---------------------------------------------------------------------------
__global__ __launch_bounds__(256) void k_attn2(
    const float* __restrict__ qkv, float* __restrict__ attn) {
  __shared__ float qs[32 * 32];
  int blk = blockIdx.x;
  int sg = blk & 7, bh = blk >> 3, h = bh & 7, b = bh >> 3;
  int tid = threadIdx.x;
  {
    int r = tid >> 3, c4 = tid & 7;
    float4 v = *(const float4*)(qkv + ((size_t)(b * 256 + sg * 32 + r)) * 768 + h * 32 + c4 * 4);
    *(float4*)&qs[r * 32 + c4 * 4] = v;
  }
  __syncthreads();
  int lane = tid & 63, w = tid >> 6;
  int r0 = w * 8;
  float sc[8][4];
#pragma unroll
  for (int r = 0; r < 8; ++r)
#pragma unroll
    for (int tt = 0; tt < 4; ++tt) sc[r][tt] = 0.f;
#pragma unroll
  for (int tt = 0; tt < 4; ++tt) {
    int t = tt * 64 + lane;
    const float4* kp = (const float4*)(qkv + ((size_t)(b * 256 + t)) * 768 + 256 + h * 32);
#pragma unroll
    for (int d4 = 0; d4 < 8; ++d4) {
      float4 kv = kp[d4];
#pragma unroll
      for (int r = 0; r < 8; ++r) {
        float4 qv = *(const float4*)&qs[(r0 + r) * 32 + d4 * 4];
        sc[r][tt] += qv.x * kv.x + qv.y * kv.y + qv.z * kv.z + qv.w * kv.w;
      }
    }
  }
  const float scale = 0.17677669529663689f;
  float* arow_base = attn + ((size_t)(bh * 256 + sg * 32 + r0)) * 256;
  for (int r = 0; r < 8; ++r) {
    float v0 = sc[r][0] * scale, v1 = sc[r][1] * scale;
    float v2 = sc[r][2] * scale, v3 = sc[r][3] * scale;
    float m = fmaxf(fmaxf(v0, v1), fmaxf(v2, v3));
#pragma unroll
    for (int o = 32; o > 0; o >>= 1) m = fmaxf(m, __shfl_xor(m, o, 64));
    float e0 = expf(v0 - m), e1 = expf(v1 - m), e2 = expf(v2 - m), e3 = expf(v3 - m);
    float s = e0 + e1 + e2 + e3;
#pragma unroll
    for (int o = 32; o > 0; o >>= 1) s += __shfl_xor(s, o, 64);
    float inv = 1.f / s;
    float* arow = arow_base + r * 256;
    arow[lane] = e0 * inv;
    arow[64 + lane] = e1 * inv;
    arow[128 + lane] = e2 * inv;
    arow[192 + lane] = e3 * inv;
  }
}

// ---------------------------------------------------------------------------
// K4b: ctx = attn @ v (fp32, unchanged)
// ---------------------------------------------------------------------------
__global__ __launch_bounds__(256) void k_ctx2(
    const float* __restrict__ attn, const float* __restrict__ qkv,
    float* __restrict__ ctx) {
  __shared__ float vs[256 * 16];
  __shared__ float ps[128 * 33];
  int blk = blockIdx.x;
  int dh = blk & 1, sh = (blk >> 1) & 1, bh = blk >> 2, h = bh & 7, b = bh >> 3;
  int tid = threadIdx.x;
#pragma unroll
  for (int k = 0; k < 4; ++k) {
    int f = tid + k * 256;
    int t = f >> 2, c4 = f & 3;
    float4 v = *(const float4*)(qkv + ((size_t)(b * 256 + t)) * 768 + 512 + h * 32 + dh * 16 + c4 * 4);
    *(float4*)&vs[t * 16 + c4 * 4] = v;
  }
  int lane = tid & 63, wv = tid >> 6;
  float a0x = 0, a0y = 0, a0z = 0, a0w = 0;
  float a1x = 0, a1y = 0, a1z = 0, a1w = 0;
  int s0l = 2 * lane, s1l = 2 * lane + 1;
  const float* abase = attn + (((size_t)bh) << 16) + (size_t)(sh * 128) * 256;
  for (int tc = 0; tc < 8; ++tc) {
    __syncthreads();
#pragma unroll
    for (int k = 0; k < 4; ++k) {
      int f = tid + k * 256;
      int r = f >> 3, c4 = f & 7;
      float4 p = *(const float4*)(abase + (size_t)r * 256 + tc * 32 + c4 * 4);
      int la = r * 33 + c4 * 4;
      ps[la] = p.x; ps[la + 1] = p.y; ps[la + 2] = p.z; ps[la + 3] = p.w;
    }
    __syncthreads();
#pragma unroll
    for (int t = 0; t < 32; ++t) {
      int tg = tc * 32 + t;
      float4 vv = *(const float4*)&vs[tg * 16 + wv * 4];
      float p0 = ps[s0l * 33 + t], p1 = ps[s1l * 33 + t];
      a0x += p0 * vv.x; a0y += p0 * vv.y; a0z += p0 * vv.z; a0w += p0 * vv.w;
      a1x += p1 * vv.x; a1y += p1 * vv.y; a1z += p1 * vv.z; a1w += p1 * vv.w;
    }
  }
  int srow0 = sh * 128 + s0l;
  float* c0 = ctx + ((size_t)(b * 256 + srow0)) * 256 + h * 32 + dh * 16 + wv * 4;
  float* c1 = c0 + 256;
  c0[0] = a0x; c0[1] = a0y; c0[2] = a0z; c0[3] = a0w;
  c1[0] = a1x; c1[1] = a1y; c1[2] = a1z; c1[3] = a1w;
}

// ---------------------------------------------------------------------------
// K4c: attn_weights = mean over heads (float4)
// ---------------------------------------------------------------------------
__global__ __launch_bounds__(256) void k_attn_mean(
    const float* __restrict__ attn, float* __restrict__ out_aw) {
  int idx = blockIdx.x * 256 + threadIdx.x;
  int b = idx >> 14;
  int st4 = idx & 16383;
  const float4* base = (const float4*)(attn + ((size_t)b << 19));
  float sx = 0, sy = 0, sz = 0, sw = 0;
#pragma unroll
  for (int h = 0; h < 8; ++h) {
    float4 v = base[h * 16384 + st4];
    sx += v.x; sy += v.y; sz += v.z; sw += v.w;
  }
  float4 r; r.x = sx * 0.125f; r.y = sy * 0.125f; r.z = sz * 0.125f; r.w = sw * 0.125f;
  ((float4*)out_aw)[idx] = r;
}

// ---------------------------------------------------------------------------
// K6: poolctx = mean over s of ctx  (pooling is linear; out-proj folded into
// k_heads2 — 'attended' never materialized)
// ---------------------------------------------------------------------------
__global__ __launch_bounds__(256) void k_poolctx(
    const float* __restrict__ ctx, float* __restrict__ poolctx) {
  int b = blockIdx.x, j = threadIdx.x;
  float s = 0.f;
  for (int t = 0; t < 256; ++t) s += ctx[((size_t)(b * 256 + t)) * 256 + j];
  poolctx[b * 256 + j] = s * (1.f / 256.f);
}

// ---------------------------------------------------------------------------
// K7: pooled = poolctx @ out_w^T + out_b ; cons & hall heads
// ---------------------------------------------------------------------------
__global__ __launch_bounds__(256) void k_heads2(
    const float* __restrict__ poolctx,
    const float* __restrict__ outw, const float* __restrict__ outb,
    const float* __restrict__ cw1, const float* __restrict__ cb1,
    const float* __restrict__ cw2, const float* __restrict__ cb2,
    const float* __restrict__ hw1, const float* __restrict__ hb1,
    const float* __restrict__ hw2, const float* __restrict__ hb2,
    float* __restrict__ out) {
  int b = blockIdx.x, j = threadIdx.x;
  __shared__ float pc[256];
  __shared__ float ps[256];
  __shared__ float red[4];
  pc[j] = poolctx[b * 256 + j];
  __syncthreads();
  float s = outb[j];
  const float4* wr = (const float4*)(outw + (size_t)j * 256);
  for (int k4 = 0; k4 < 64; ++k4) {
    float4 wv = wr[k4];
    const float* p = pc + k4 * 4;
    s += p[0] * wv.x + p[1] * wv.y + p[2] * wv.z + p[3] * wv.w;
  }
  ps[j] = s;
  __syncthreads();
  int jj = j & 127;
  bool isH = j >= 128;
  const float* w1 = isH ? hw1 : cw1;
  const float* bb1 = isH ? hb1 : cb1;
  const float* w2 = isH ? hw2 : cw2;
  float a = bb1[jj];
  const float4* w1r = (const float4*)(w1 + (size_t)jj * 256);
  for (int k4 = 0; k4 < 64; ++k4) {
    float4 wv = w1r[k4];
    const float* p = ps + k4 * 4;
    a += p[0] * wv.x + p[1] * wv.y + p[2] * wv.z + p[3] * wv.w;
  }
  float v = fmaxf(a, 0.f) * w2[jj];
#pragma unroll
  for (int o = 32; o > 0; o >>= 1) v += __shfl_xor(v, o, 64);
  if ((j & 63) == 0) red[j >> 6] = v;
  __syncthreads();
  if (j == 0) {
    float c = red[0] + red[1] + cb2[0];
    float h = red[2] + red[3] + hb2[0];
    out[b] = 1.f / (1.f + expf(-c));
    out[8 + b] = 1.f / (1.f + expf(-h));
  }
}

// ---------------------------------------------------------------------------
// K9: pair scores, LDS-tiled (fp32, unchanged)
// ---------------------------------------------------------------------------
__global__ __launch_bounds__(256) void k_pairs(
    const float* __restrict__ amat, const float* __restrict__ bmat,
    const float* __restrict__ cw2, const float* __restrict__ cb2,
    float* __restrict__ M) {
  __shared__ float As[32 * 130];
  __shared__ float Bs[32 * 130];
  __shared__ float w2s[256];
  int blk = blockIdx.x;
  int b = blk / 36, tix = blk % 36;
  int it = 0, rem = tix;
  while (rem >= 8 - it) { rem -= 8 - it; ++it; }
  int jt = it + rem;
  int tid = threadIdx.x;
  int tj = tid & 15, ti = tid >> 4;
  w2s[tid] = cw2[tid];
  float acc00 = 0, acc01 = 0, acc10 = 0, acc11 = 0;
  const float* Ab = amat + ((size_t)(b * 256 + it * 32)) * 256;
  const float* Bb = bmat + ((size_t)(b * 256 + jt * 32)) * 256;
  for (int ch = 0; ch < 2; ++ch) {
    __syncthreads();
#pragma unroll
    for (int k = 0; k < 4; ++k) {
      int f = tid + k * 256;
      int r = f >> 5, c4 = f & 31;
      float4 va = *(const float4*)(Ab + (size_t)r * 256 + ch * 128 + c4 * 4);
      float4 vb = *(const float4*)(Bb + (size_t)r * 256 + ch * 128 + c4 * 4);
      int la = r * 130 + c4 * 4;
      *(float2*)&As[la] = make_float2(va.x, va.y);
      *(float2*)&As[la + 2] = make_float2(va.z, va.w);
      *(float2*)&Bs[la] = make_float2(vb.x, vb.y);
      *(float2*)&Bs[la + 2] = make_float2(vb.z, vb.w);
    }
    __syncthreads();
    const float* a0 = As + (2 * ti) * 130;
    const float* a1 = a0 + 130;
    const float* b0 = Bs + (2 * tj) * 130;
    const float* b1 = b0 + 130;
    const float* w2c = w2s + ch * 128;
    for (int d = 0; d < 128; d += 4) {
#pragma unroll
      for (int k = 0; k < 4; ++k) {
        float w = w2c[d + k];
        float av0 = a0[d + k], av1 = a1[d + k];
        float bv0 = b0[d + k], bv1 = b1[d + k];
        acc00 += fmaxf(av0 + bv0, 0.f) * w;
        acc01 += fmaxf(av0 + bv1, 0.f) * w;
        acc10 += fmaxf(av1 + bv0, 0.f) * w;
        acc11 += fmaxf(av1 + bv1, 0.f) * w;
      }
    }
  }
  float c2 = cb2[0];
  float s00 = 1.f / (1.f + expf(-(acc00 + c2)));
  float s01 = 1.f / (1.f + expf(-(acc01 + c2)));
  float s10 = 1.f / (1.f + expf(-(acc10 + c2)));
  float s11 = 1.f / (1.f + expf(-(acc11 + c2)));
  float* Mb = M + ((size_t)b << 16);
  int i0 = it * 32 + 2 * ti, i1 = i0 + 1;
  int j0 = jt * 32 + 2 * tj, j1 = j0 + 1;
  if (it != jt) {
    Mb[i0 * 256 + j0] = s00; Mb[j0 * 256 + i0] = s00;
    Mb[i0 * 256 + j1] = s01; Mb[j1 * 256 + i0] = s01;
    Mb[i1 * 256 + j0] = s10; Mb[j0 * 256 + i1] = s10;
    Mb[i1 * 256 + j1] = s11; Mb[j1 * 256 + i1] = s11;
  } else {
    if (j0 > i0) { Mb[i0 * 256 + j0] = s00; Mb[j0 * 256 + i0] = s00; }
    else if (j0 == i0) Mb[i0 * 256 + j0] = 0.f;
    if (j1 > i0) { Mb[i0 * 256 + j1] = s01; Mb[j1 * 256 + i0] = s01; }
    if (j0 > i1) { Mb[i1 * 256 + j0] = s10; Mb[j0 * 256 + i1] = s10; }
    if (j1 > i1) { Mb[i1 * 256 + j1] = s11; Mb[j1 * 256 + i1] = s11; }
    else if (j1 == i1) Mb[i1 * 256 + j1] = 0.f;
  }
}

// ---------------------------------------------------------------------------
extern "C" void kernel_launch(void* const* d_in, const int* in_sizes, int n_in,
                              void* d_out, int out_size, void* d_ws, size_t ws_size,
                              hipStream_t stream) {
  const float* me        = (const float*)d_in[0];
  const float* enc_w1    = (const float*)d_in[1];
  const float* enc_b1    = (const float*)d_in[2];
  const float* ln_g      = (const float*)d_in[3];
  const float* ln_b      = (const float*)d_in[4];
  const float* enc_w2    = (const float*)d_in[5];
  const float* enc_b2    = (const float*)d_in[6];
  const float* in_proj_w = (const float*)d_in[7];
  const float* in_proj_b = (const float*)d_in[8];
  const float* out_w     = (const float*)d_in[9];
  const float* out_b     = (const float*)d_in[10];
  const float* cons_w1   = (const float*)d_in[11];
  const float* cons_b1   = (const float*)d_in[12];
  const float* cons_w2   = (const float*)d_in[13];
  const float* cons_b2   = (const float*)d_in[14];
  const float* hall_w1   = (const float*)d_in[15];
  const float* hall_b1   = (const float*)d_in[16];
  const float* hall_w2   = (const float*)d_in[17];
  const float* hall_b2   = (const float*)d_in[18];
  const float* con_w1    = (const float*)d_in[19];
  const float* con_b1    = (const float*)d_in[20];
  const float* con_w2    = (const float*)d_in[21];
  const float* con_b2    = (const float*)d_in[22];

  // workspace layout (float offsets)
  float* ws = (float*)d_ws;
  float* r       = ws;                 // 524288
  float* mf      = ws + 524288;        // 524288
  float* qkv     = ws + 1048576;       // 1572864
  float* attn    = ws + 2621440;       // 4194304
  float* ctx     = ws + 6815744;       // 524288
  unsigned short* wbf = (unsigned short*)(ws + 7340032);  // 524288 bf16 = 262144 floats
  float* poolctx = ws + 7602176;       // 2048
  float* amat    = ws + 7866368;       // 524288
  float* bmat    = ws + 8390656;       // 524288

  unsigned short* wb1  = wbf;            // 131072 (enc_w1)
  unsigned short* wb2  = wbf + 131072;   // 65536  (enc_w2)
  unsigned short* wqk  = wbf + 196608;   // 196608 (in_proj_w)
  unsigned short* wab  = wbf + 393216;   // 131072 (con_w1 repacked)

  float* out    = (float*)d_out;
  float* out_M  = out + 16;
  float* out_aw = out + 16 + 524288;

  k_cvt<<<512, 256, 0, stream>>>(enc_w1, enc_w2, in_proj_w, con_w1, wbf);
  k_enc1_mfma<<<128, 256, 0, stream>>>(me, wb1, enc_b1, ln_g, ln_b, r);
  k_lin256<<<dim3(128, 1), 256, 0, stream>>>(r, wb2, enc_b2, mf, 256);
  k_lin256<<<dim3(128, 3), 256, 0, stream>>>(mf, wqk, in_proj_b, qkv, 768);
  k_attn2<<<512, 256, 0, stream>>>(qkv, attn);
  k_ctx2<<<256, 256, 0, stream>>>(attn, qkv, ctx);
  k_attn_mean<<<512, 256, 0, stream>>>(attn, out_aw);
  k_ab_mfma<<<dim3(128, 2), 256, 0, stream>>>(mf, wab, con_b1, amat, bmat);
  k_poolctx<<<8, 256, 0, stream>>>(ctx, poolctx);
  k_heads2<<<8, 256, 0, stream>>>(poolctx, out_w, out_b,
                                  cons_w1, cons_b1, cons_w2, cons_b2,
                                  hall_w1, hall_b1, hall_w2, hall_b2, out);
  k_pairs<<<288, 256, 0, stream>>>(amat, bmat, con_w2, con_b2, out_M);
}